// Round 1
// baseline (2163.258 us; speedup 1.0000x reference)
//
#include <hip/hip_runtime.h>

// Problem constants (B,T,E,H,D fixed by the reference)
constexpr int Bc = 4, Tc = 2048, Ec = 1024, Hc = 16, Dc = 64;

// ---------------------------------------------------------------------------
// GEMM: C[M,N] = A[M,K] @ W[K,N] + bias.  BM=BN=128, BK=16, 256 threads,
// 8x8 micro-tile per thread (rows {4tm..+3, 64+4tm..+3}, cols likewise).
// QKV=true scatters the output into Q/K/V buffers laid out [B,H,T,D].
// ---------------------------------------------------------------------------
template <bool QKV>
__global__ __launch_bounds__(256) void gemm_k(
    const float* __restrict__ A, const float* __restrict__ W,
    const float* __restrict__ bias, float* __restrict__ C,
    float* __restrict__ Qb, float* __restrict__ Kb, float* __restrict__ Vb,
    int M, int N, int K)
{
    __shared__ float As[16][132];   // As[k][m], pitch 132 -> conflict-free transpose
    __shared__ float Bs[16][128];   // Bs[k][n]

    const int tid = threadIdx.x;
    const int tm = tid >> 4, tn = tid & 15;
    const int m0 = blockIdx.y * 128, n0 = blockIdx.x * 128;

    float acc[8][8];
#pragma unroll
    for (int i = 0; i < 8; ++i)
#pragma unroll
        for (int j = 0; j < 8; ++j) acc[i][j] = 0.f;

    for (int k0 = 0; k0 < K; k0 += 16) {
        // A tile 128x16, transposed into As[k][m]
#pragma unroll
        for (int l = 0; l < 2; ++l) {
            int idx = tid + 256 * l;            // 0..511
            int row = idx >> 2, c4 = idx & 3;
            const float4 v = *(const float4*)(A + (size_t)(m0 + row) * K + k0 + 4 * c4);
            As[4 * c4 + 0][row] = v.x;
            As[4 * c4 + 1][row] = v.y;
            As[4 * c4 + 2][row] = v.z;
            As[4 * c4 + 3][row] = v.w;
        }
        // B tile 16x128
#pragma unroll
        for (int l = 0; l < 2; ++l) {
            int idx = tid + 256 * l;
            int kk = idx >> 5, n4 = idx & 31;
            *(float4*)&Bs[kk][4 * n4] =
                *(const float4*)(W + (size_t)(k0 + kk) * N + n0 + 4 * n4);
        }
        __syncthreads();

#pragma unroll
        for (int kk = 0; kk < 16; ++kk) {
            float4 a0 = *(const float4*)&As[kk][4 * tm];
            float4 a1 = *(const float4*)&As[kk][64 + 4 * tm];
            float4 b0 = *(const float4*)&Bs[kk][4 * tn];
            float4 b1 = *(const float4*)&Bs[kk][64 + 4 * tn];
            float av[8] = {a0.x, a0.y, a0.z, a0.w, a1.x, a1.y, a1.z, a1.w};
            float bv[8] = {b0.x, b0.y, b0.z, b0.w, b1.x, b1.y, b1.z, b1.w};
#pragma unroll
            for (int i = 0; i < 8; ++i)
#pragma unroll
                for (int j = 0; j < 8; ++j)
                    acc[i][j] = fmaf(av[i], bv[j], acc[i][j]);
        }
        __syncthreads();
    }

    // epilogue: bias + store
#pragma unroll
    for (int ih = 0; ih < 2; ++ih)
#pragma unroll
        for (int i = 0; i < 4; ++i) {
            const int m = m0 + 64 * ih + 4 * tm + i;
#pragma unroll
            for (int jh = 0; jh < 2; ++jh) {
                const int n = n0 + 64 * jh + 4 * tn;
                float4 bv = *(const float4*)(bias + n);
                float4 r;
                r.x = acc[ih * 4 + i][jh * 4 + 0] + bv.x;
                r.y = acc[ih * 4 + i][jh * 4 + 1] + bv.y;
                r.z = acc[ih * 4 + i][jh * 4 + 2] + bv.z;
                r.w = acc[ih * 4 + i][jh * 4 + 3] + bv.w;
                if (QKV) {
                    const int b = m >> 11, t = m & 2047;     // T = 2048
                    const int sel = n >> 10;                 // uniform per block
                    const int cq = n & 1023;
                    const int h = cq >> 6, d = cq & 63;      // float4 stays in one head
                    float* dst = (sel == 0) ? Qb : (sel == 1) ? Kb : Vb;
                    *(float4*)(dst + (((size_t)(b * Hc + h)) * Tc + t) * Dc + d) = r;
                } else {
                    *(float4*)(C + (size_t)m * N + n) = r;
                }
            }
        }
}

// ---------------------------------------------------------------------------
// Flash attention, fp32. One block per (b, h, 64-row Q tile); 256 threads,
// thread (tm,tn) owns a 4x4 micro-tile: rows 4tm+i, cols 4tn+j.
// Q/K tiles stored with XOR-swizzled 4-float column blocks so the stride-4
// row reads are <=2-way bank conflicts. Online softmax in registers.
// ---------------------------------------------------------------------------
__global__ __launch_bounds__(256) void attn_k(
    const float* __restrict__ Qg, const float* __restrict__ Kg,
    const float* __restrict__ Vg, float* __restrict__ Aout)
{
    __shared__ float Qs[64][64];
    __shared__ float Ks[64][64];
    __shared__ float Vs[64][64];
    __shared__ float Ps[64][64];

    const int tid = threadIdx.x;
    const int tm = tid >> 4, tn = tid & 15;
    const int tq = blockIdx.x, h = blockIdx.y, b = blockIdx.z;
    const int q0 = tq * 64;
    const size_t headoff = ((size_t)(b * Hc + h)) * Tc * Dc;

    // stage Q tile (swizzled)
    {
        const float4* Qg4 = (const float4*)(Qg + headoff + (size_t)q0 * Dc);
#pragma unroll
        for (int l = 0; l < 4; ++l) {
            int idx = tid + 256 * l;           // 0..1023
            int r = idx >> 4, c4 = idx & 15;
            int c4s = c4 ^ ((r >> 2) & 7);
            *(float4*)&Qs[r][4 * c4s] = Qg4[idx];
        }
    }

    float o[4][4];
    float mrun[4], lrun[4];
#pragma unroll
    for (int i = 0; i < 4; ++i) {
        mrun[i] = -1e30f;
        lrun[i] = 0.f;
#pragma unroll
        for (int j = 0; j < 4; ++j) o[i][j] = 0.f;
    }

    for (int st = 0; st <= tq; ++st) {
        // stage K (swizzled) and V (natural) tiles
        {
            const float4* Kg4 = (const float4*)(Kg + headoff + (size_t)st * 64 * Dc);
            const float4* Vg4 = (const float4*)(Vg + headoff + (size_t)st * 64 * Dc);
#pragma unroll
            for (int l = 0; l < 4; ++l) {
                int idx = tid + 256 * l;
                int r = idx >> 4, c4 = idx & 15;
                int c4s = c4 ^ ((r >> 2) & 7);
                *(float4*)&Ks[r][4 * c4s] = Kg4[idx];
                *(float4*)&Vs[r][4 * c4] = Vg4[idx];
            }
        }
        __syncthreads();

        // scores S = Q K^T (4x4 per thread), k-blocked by 4
        float s[4][4];
#pragma unroll
        for (int i = 0; i < 4; ++i)
#pragma unroll
            for (int j = 0; j < 4; ++j) s[i][j] = 0.f;

#pragma unroll
        for (int kc = 0; kc < 16; ++kc) {
            float4 qv[4], kv[4];
#pragma unroll
            for (int i = 0; i < 4; ++i)
                qv[i] = *(const float4*)&Qs[4 * tm + i][4 * (kc ^ (tm & 7))];
#pragma unroll
            for (int j = 0; j < 4; ++j)
                kv[j] = *(const float4*)&Ks[4 * tn + j][4 * (kc ^ (tn & 7))];
#pragma unroll
            for (int i = 0; i < 4; ++i)
#pragma unroll
                for (int j = 0; j < 4; ++j)
                    s[i][j] += qv[i].x * kv[j].x + qv[i].y * kv[j].y +
                               qv[i].z * kv[j].z + qv[i].w * kv[j].w;
        }

        const float scale = 0.125f;              // 1/sqrt(64)
        const bool diag = (st == tq);
#pragma unroll
        for (int i = 0; i < 4; ++i)
#pragma unroll
            for (int j = 0; j < 4; ++j) {
                float v = s[i][j] * scale;
                if (diag && (4 * tn + j > 4 * tm + i)) v = -1e30f;  // causal mask
                s[i][j] = v;
            }

        // online softmax: row stats across the 16 lanes holding each row
        float alpha[4];
#pragma unroll
        for (int i = 0; i < 4; ++i) {
            float tmax = fmaxf(fmaxf(s[i][0], s[i][1]), fmaxf(s[i][2], s[i][3]));
#pragma unroll
            for (int off = 1; off < 16; off <<= 1)
                tmax = fmaxf(tmax, __shfl_xor(tmax, off));
            const float mnew = fmaxf(mrun[i], tmax);
            alpha[i] = __expf(mrun[i] - mnew);
            mrun[i] = mnew;
            float tsum = 0.f;
#pragma unroll
            for (int j = 0; j < 4; ++j) {
                s[i][j] = __expf(s[i][j] - mnew);
                tsum += s[i][j];
            }
#pragma unroll
            for (int off = 1; off < 16; off <<= 1)
                tsum += __shfl_xor(tsum, off);
            lrun[i] = lrun[i] * alpha[i] + tsum;
        }

        // publish P, rescale O
#pragma unroll
        for (int i = 0; i < 4; ++i)
            *(float4*)&Ps[4 * tm + i][4 * tn] =
                make_float4(s[i][0], s[i][1], s[i][2], s[i][3]);
#pragma unroll
        for (int i = 0; i < 4; ++i)
#pragma unroll
            for (int j = 0; j < 4; ++j) o[i][j] *= alpha[i];
        __syncthreads();

        // O += P @ V, s-blocked by 4
#pragma unroll
        for (int sc = 0; sc < 16; ++sc) {
            float pv[4][4], vv[4][4];
#pragma unroll
            for (int i = 0; i < 4; ++i) {
                float4 t = *(const float4*)&Ps[4 * tm + i][4 * sc];
                pv[i][0] = t.x; pv[i][1] = t.y; pv[i][2] = t.z; pv[i][3] = t.w;
            }
#pragma unroll
            for (int sj = 0; sj < 4; ++sj) {
                float4 t = *(const float4*)&Vs[4 * sc + sj][4 * tn];
                vv[sj][0] = t.x; vv[sj][1] = t.y; vv[sj][2] = t.z; vv[sj][3] = t.w;
            }
#pragma unroll
            for (int i = 0; i < 4; ++i)
#pragma unroll
                for (int j = 0; j < 4; ++j) {
                    o[i][j] = fmaf(pv[i][0], vv[0][j], o[i][j]);
                    o[i][j] = fmaf(pv[i][1], vv[1][j], o[i][j]);
                    o[i][j] = fmaf(pv[i][2], vv[2][j], o[i][j]);
                    o[i][j] = fmaf(pv[i][3], vv[3][j], o[i][j]);
                }
        }
        __syncthreads();
    }

    // normalize + store into [B,T,E] layout (col = h*64 + d)
    const int mbase = b * Tc + q0;
#pragma unroll
    for (int i = 0; i < 4; ++i) {
        const float inv = 1.f / lrun[i];
        float4 r = make_float4(o[i][0] * inv, o[i][1] * inv,
                               o[i][2] * inv, o[i][3] * inv);
        *(float4*)(Aout + (size_t)(mbase + 4 * tm + i) * Ec + h * Dc + 4 * tn) = r;
    }
}

// ---------------------------------------------------------------------------
extern "C" void kernel_launch(void* const* d_in, const int* in_sizes, int n_in,
                              void* d_out, int out_size, void* d_ws, size_t ws_size,
                              hipStream_t stream)
{
    const float* x     = (const float*)d_in[0];
    const float* w_qkv = (const float*)d_in[1];
    const float* b_qkv = (const float*)d_in[2];
    const float* w_out = (const float*)d_in[3];
    const float* b_out = (const float*)d_in[4];
    float* out = (float*)d_out;

    const size_t QSZ = (size_t)Bc * Hc * Tc * Dc;   // 8M floats
    float* Qb = (float*)d_ws;
    float* Kb = Qb + QSZ;
    float* Vb = Kb + QSZ;
    float* Ab = Vb + QSZ;                            // attention out, [M][E]

    // 1) QKV projection, scatter to [B,H,T,D]
    gemm_k<true><<<dim3(3072 / 128, 8192 / 128), 256, 0, stream>>>(
        x, w_qkv, b_qkv, nullptr, Qb, Kb, Vb, 8192, 3072, 1024);

    // 2) causal flash attention -> Ab [8192][1024]
    attn_k<<<dim3(Tc / 64, Hc, Bc), 256, 0, stream>>>(Qb, Kb, Vb, Ab);

    // 3) output projection
    gemm_k<false><<<dim3(1024 / 128, 8192 / 128), 256, 0, stream>>>(
        Ab, w_out, b_out, out, nullptr, nullptr, nullptr, 8192, 1024, 1024);
}

// Round 6
// 446.652 us; speedup vs baseline: 4.8433x; 4.8433x over previous
//
#include <hip/hip_runtime.h>

typedef short bf16x8 __attribute__((ext_vector_type(8)));
typedef float f32x4 __attribute__((ext_vector_type(4)));

constexpr int Tc = 2048, Ec = 1024, Hc = 16, Dc = 64;

__device__ __forceinline__ short f2b(float f) {  // fp32 -> bf16 RNE
    unsigned u = __builtin_bit_cast(unsigned, f);
    unsigned r = (u + 0x7FFFu + ((u >> 16) & 1u)) >> 16;
    return (short)r;
}
__device__ __forceinline__ float b2f(short s) {
    unsigned u = ((unsigned)(unsigned short)s) << 16;
    return __builtin_bit_cast(float, u);
}
__device__ __forceinline__ void gll16(const void* g, void* l) {
    // global -> LDS direct, 16B/lane; LDS dest = wave-uniform base + lane*16
    __builtin_amdgcn_global_load_lds(
        (const __attribute__((address_space(1))) unsigned int*)g,
        (__attribute__((address_space(3))) unsigned int*)l, 16, 0, 0);
}

// ---------------------------------------------------------------------------
__global__ __launch_bounds__(256) void convert_f32_bf16(
    const float* __restrict__ in, short* __restrict__ out, int n)
{
    int i = (blockIdx.x * 256 + threadIdx.x) * 4;
    if (i < n) {
        float4 v = *(const float4*)(in + i);
        short4 o;
        o.x = f2b(v.x); o.y = f2b(v.y); o.z = f2b(v.z); o.w = f2b(v.w);
        *(short4*)(out + i) = o;
    }
}

// in [K][N] fp32 -> out [N][K] bf16 (i.e. B^T for the GEMM)
__global__ __launch_bounds__(256) void transpose_conv(
    const float* __restrict__ in, short* __restrict__ out, int K, int N)
{
    __shared__ float t[64][65];
    const int k0 = blockIdx.y * 64, n0 = blockIdx.x * 64;
    const int tid = threadIdx.x;
#pragma unroll
    for (int rep = 0; rep < 16; ++rep) {
        int flat = rep * 256 + tid;
        int r = flat >> 6, c = flat & 63;
        t[r][c] = in[(size_t)(k0 + r) * N + n0 + c];
    }
    __syncthreads();
#pragma unroll
    for (int rep = 0; rep < 16; ++rep) {
        int flat = rep * 256 + tid;
        int r = flat >> 6, c = flat & 63;
        out[(size_t)(n0 + r) * K + k0 + c] = f2b(t[c][r]);
    }
}

// ---------------------------------------------------------------------------
// bf16 GEMM, m97 structure: BM=BN=128, BK=32, 4 waves (2x2), 4x4 frags/wave,
// 16x16x32 MFMA, global_load_lds staging, 2 barriers per K-step.
// A [M][K] bf16 row-major, Bt [N][K] bf16 row-major (= B^T).
// MODE 0: scatter bf16 to Q[B,H,T,D], K[B,H,T,D], Vt[B,H,D,T] (+bias)
// MODE 1: fp32 C[M][N] (+bias)
// ---------------------------------------------------------------------------
template <int MODE>
__global__ __launch_bounds__(256) void gemm_bf16(
    const short* __restrict__ A, const short* __restrict__ Bt,
    const float* __restrict__ bias,
    short* __restrict__ Qb, short* __restrict__ Kb, short* __restrict__ Vt,
    float* __restrict__ C, int M, int N, int K)
{
    __shared__ __align__(16) short As[128 * 32];
    __shared__ __align__(16) short Bs[128 * 32];

    const int tid = threadIdx.x;
    const int lane = tid & 63, w = tid >> 6;
    const int l15 = lane & 15, l4 = lane >> 4;
    const int wm = w >> 1, wn = w & 1;
    const int m0 = blockIdx.y * 128, n0 = blockIdx.x * 128;

    f32x4 acc[4][4];
#pragma unroll
    for (int i = 0; i < 4; ++i)
#pragma unroll
        for (int j = 0; j < 4; ++j) acc[i][j] = (f32x4)0.f;

    for (int k0 = 0; k0 < K; k0 += 32) {
        __syncthreads();
#pragma unroll
        for (int i = 0; i < 2; ++i) {
            const int slot = w * 64 + i * 256 + lane;      // 0..511
            const int row = slot >> 2, cb = slot & 3;      // 4x16B per 32-col row
            char* ldst = (char*)As + (w * 64 + i * 256) * 16;  // wave-uniform
            gll16(A + (size_t)(m0 + row) * K + k0 + cb * 8, ldst);
            char* ldst2 = (char*)Bs + (w * 64 + i * 256) * 16;
            gll16(Bt + (size_t)(n0 + row) * K + k0 + cb * 8, ldst2);
        }
        __syncthreads();

        bf16x8 af[4], bfr[4];
#pragma unroll
        for (int f = 0; f < 4; ++f) {
            af[f]  = *(const bf16x8*)((const char*)As + ((wm * 64 + f * 16 + l15) * 32 + l4 * 8) * 2);
            bfr[f] = *(const bf16x8*)((const char*)Bs + ((wn * 64 + f * 16 + l15) * 32 + l4 * 8) * 2);
        }
#pragma unroll
        for (int fm = 0; fm < 4; ++fm)
#pragma unroll
            for (int fn = 0; fn < 4; ++fn)
                acc[fm][fn] = __builtin_amdgcn_mfma_f32_16x16x32_bf16(
                    af[fm], bfr[fn], acc[fm][fn], 0, 0, 0);
    }

    // epilogue: C/D layout col = lane&15, row = (lane>>4)*4 + r
#pragma unroll
    for (int fn = 0; fn < 4; ++fn) {
        const int n = n0 + wn * 64 + fn * 16 + l15;
        const float bv = bias[n];
        if (MODE == 0) {
            const int sel = n >> 10, nq = n & 1023, hh = nq >> 6, dd = nq & 63;
#pragma unroll
            for (int fm = 0; fm < 4; ++fm)
#pragma unroll
                for (int r = 0; r < 4; ++r) {
                    const int mrow = m0 + wm * 64 + fm * 16 + l4 * 4 + r;
                    const short hv = f2b(acc[fm][fn][r] + bv);
                    const int bb = mrow >> 11, tt = mrow & 2047;
                    const size_t bh = (size_t)(bb * Hc + hh);
                    if (sel == 0)      Qb[(bh * Tc + tt) * Dc + dd] = hv;
                    else if (sel == 1) Kb[(bh * Tc + tt) * Dc + dd] = hv;
                    else               Vt[(bh * Dc + dd) * Tc + tt] = hv;
                }
        } else {
#pragma unroll
            for (int fm = 0; fm < 4; ++fm)
#pragma unroll
                for (int r = 0; r < 4; ++r) {
                    const int mrow = m0 + wm * 64 + fm * 16 + l4 * 4 + r;
                    C[(size_t)mrow * N + n] = acc[fm][fn][r] + bv;
                }
        }
    }
}

// ---------------------------------------------------------------------------
// Flash attention, bf16 MFMA. Block = (64 q-rows)x(b,h); 4 waves, wave w owns
// q-rows [tq*64 + w*16, +16). K tiles and Vt (d-major) tiles staged via
// global_load_lds with pre-swizzled source (XOR of 16B block by row&7) so
// ds_read_b128 fragment reads are ~2-way conflicts. Online softmax in regs.
// ---------------------------------------------------------------------------
__global__ __launch_bounds__(256) void attn_mfma(
    const short* __restrict__ Qg, const short* __restrict__ Kg,
    const short* __restrict__ Vtg, short* __restrict__ Ab)
{
    __shared__ __align__(16) short Ks[64 * 64];
    __shared__ __align__(16) short Vs[64 * 64];       // Vt tile: rows d, cols s
    __shared__ __align__(16) short Ps[4][16 * 64];    // per-wave P

    const int tid = threadIdx.x;
    const int lane = tid & 63, w = tid >> 6;
    const int l15 = lane & 15, l4 = lane >> 4;
    const int tq = (int)gridDim.x - 1 - (int)blockIdx.x;  // long blocks first
    const int h = blockIdx.y, b = blockIdx.z;
    const size_t base = (size_t)(b * Hc + h) * Tc * Dc;   // same extent for Q,K,Vt
    const int q0 = tq * 64 + w * 16;

    // Q fragments in registers, pre-scaled by 1/sqrt(D)=0.125 (exact in bf16)
    bf16x8 qf[2];
    {
        const short* qp = Qg + base + (size_t)(q0 + l15) * Dc + l4 * 8;
        qf[0] = *(const bf16x8*)qp;
        qf[1] = *(const bf16x8*)(qp + 32);
#pragma unroll
        for (int e = 0; e < 8; ++e) {
            qf[0][e] = f2b(b2f(qf[0][e]) * 0.125f);
            qf[1][e] = f2b(b2f(qf[1][e]) * 0.125f);
        }
    }

    f32x4 o[4];
    float mr[4], ls[4];
#pragma unroll
    for (int i = 0; i < 4; ++i) { o[i] = (f32x4)0.f; mr[i] = -1e30f; ls[i] = 0.f; }

    for (int st = 0; st <= tq; ++st) {
        __syncthreads();
#pragma unroll
        for (int i = 0; i < 2; ++i) {
            const int slot = w * 64 + i * 256 + lane;     // 0..511
            const int row = slot >> 3, cb = slot & 7;     // 8x16B per 64-col row
            const int cbs = cb ^ (row & 7);               // pre-swizzled source
            char* kdst = (char*)Ks + (w * 64 + i * 256) * 16;
            gll16(Kg + base + (size_t)(st * 64 + row) * Dc + cbs * 8, kdst);
            char* vdst = (char*)Vs + (w * 64 + i * 256) * 16;
            gll16(Vtg + base + (size_t)row * Tc + st * 64 + cbs * 8, vdst);
        }
        __syncthreads();

        // S = Q K^T  (wave's 16 rows x 64 cols)
        f32x4 s[4];
#pragma unroll
        for (int fn = 0; fn < 4; ++fn) s[fn] = (f32x4)0.f;
#pragma unroll
        for (int kf = 0; kf < 2; ++kf)
#pragma unroll
            for (int fn = 0; fn < 4; ++fn) {
                const int srow = fn * 16 + l15;
                bf16x8 kb = *(const bf16x8*)((const char*)Ks + srow * 128 +
                                             ((kf * 64 + l4 * 16) ^ ((srow & 7) << 4)));
                s[fn] = __builtin_amdgcn_mfma_f32_16x16x32_bf16(qf[kf], kb, s[fn], 0, 0, 0);
            }

        if (st == tq) {  // diagonal tile: causal mask (col > row)
#pragma unroll
            for (int fn = 0; fn < 4; ++fn)
#pragma unroll
                for (int r = 0; r < 4; ++r)
                    if (fn * 16 + l15 > w * 16 + l4 * 4 + r) s[fn][r] = -1e30f;
        }

        // online softmax, rows = l4*4 + r, 16 lanes per row
        float alpha[4];
#pragma unroll
        for (int r = 0; r < 4; ++r) {
            float tm = fmaxf(fmaxf(s[0][r], s[1][r]), fmaxf(s[2][r], s[3][r]));
#pragma unroll
            for (int off = 1; off < 16; off <<= 1)
                tm = fmaxf(tm, __shfl_xor(tm, off));
            const float mn = fmaxf(mr[r], tm);
            alpha[r] = __expf(mr[r] - mn);
            mr[r] = mn;
            float rs = 0.f;
#pragma unroll
            for (int fn = 0; fn < 4; ++fn) {
                const float p = __expf(s[fn][r] - mn);
                s[fn][r] = p;
                rs += p;
            }
#pragma unroll
            for (int off = 1; off < 16; off <<= 1)
                rs += __shfl_xor(rs, off);
            ls[r] = ls[r] * alpha[r] + rs;
        }

        // P -> bf16 -> LDS (XOR-swizzled), rescale O
        short* pw = Ps[w];
#pragma unroll
        for (int fn = 0; fn < 4; ++fn)
#pragma unroll
            for (int r = 0; r < 4; ++r) {
                const int prow = l4 * 4 + r;
                const int pcol = fn * 16 + l15;
                *(short*)((char*)pw + prow * 128 + ((pcol * 2) ^ ((prow & 7) << 4))) =
                    f2b(s[fn][r]);
                o[fn][r] *= alpha[r];
            }

        // O += P @ V   (A = P from LDS, B = Vt rows)
#pragma unroll
        for (int kf = 0; kf < 2; ++kf) {
            bf16x8 pa = *(const bf16x8*)((const char*)pw + l15 * 128 +
                                         ((kf * 64 + l4 * 16) ^ ((l15 & 7) << 4)));
#pragma unroll
            for (int fn = 0; fn < 4; ++fn) {
                const int vrow = fn * 16 + l15;
                bf16x8 vb = *(const bf16x8*)((const char*)Vs + vrow * 128 +
                                             ((kf * 64 + l4 * 16) ^ ((vrow & 7) << 4)));
                o[fn] = __builtin_amdgcn_mfma_f32_16x16x32_bf16(pa, vb, o[fn], 0, 0, 0);
            }
        }
    }

    // normalize + store bf16 [B*T][E]
#pragma unroll
    for (int r = 0; r < 4; ++r) {
        const float inv = 1.f / ls[r];
        const int gm = b * Tc + q0 + l4 * 4 + r;
#pragma unroll
        for (int fn = 0; fn < 4; ++fn)
            Ab[(size_t)gm * Ec + h * Dc + fn * 16 + l15] = f2b(o[fn][r] * inv);
    }
}

// ---------------------------------------------------------------------------
extern "C" void kernel_launch(void* const* d_in, const int* in_sizes, int n_in,
                              void* d_out, int out_size, void* d_ws, size_t ws_size,
                              hipStream_t stream)
{
    const float* x     = (const float*)d_in[0];
    const float* w_qkv = (const float*)d_in[1];
    const float* b_qkv = (const float*)d_in[2];
    const float* w_out = (const float*)d_in[3];
    const float* b_out = (const float*)d_in[4];
    float* out = (float*)d_out;

    const size_t NX = (size_t)8192 * 1024;
    short* xb  = (short*)d_ws;        // 16 MB
    short* Wtq = xb + NX;             // [3072][1024] bf16, 6 MB
    short* Wto = Wtq + (size_t)3072 * 1024;  // [1024][1024] bf16, 2 MB
    short* Qb  = Wto + (size_t)1024 * 1024;  // [B,H,T,D] bf16, 16 MB
    short* Kb  = Qb + NX;
    short* Vt  = Kb + NX;             // [B,H,D,T] bf16
    short* Ab  = Vt + NX;             // [B*T][E] bf16

    convert_f32_bf16<<<8192, 256, 0, stream>>>(x, xb, (int)NX);
    transpose_conv<<<dim3(48, 16), 256, 0, stream>>>(w_qkv, Wtq, 1024, 3072);
    transpose_conv<<<dim3(16, 16), 256, 0, stream>>>(w_out, Wto, 1024, 1024);

    gemm_bf16<0><<<dim3(24, 64), 256, 0, stream>>>(
        xb, Wtq, b_qkv, Qb, Kb, Vt, nullptr, 8192, 3072, 1024);

    attn_mfma<<<dim3(32, 16, 4), 256, 0, stream>>>(Qb, Kb, Vt, Ab);

    gemm_bf16<1><<<dim3(8, 64), 256, 0, stream>>>(
        Ab, Wto, b_out, nullptr, nullptr, nullptr, out, 8192, 1024, 1024);
}

// Round 7
// 398.720 us; speedup vs baseline: 5.4255x; 1.1202x over previous
//
#include <hip/hip_runtime.h>

typedef short bf16x8 __attribute__((ext_vector_type(8)));
typedef float f32x4 __attribute__((ext_vector_type(4)));

constexpr int Tc = 2048, Ec = 1024, Hc = 16, Dc = 64;

__device__ __forceinline__ short f2b(float f) {  // fp32 -> bf16 RNE
    unsigned u = __builtin_bit_cast(unsigned, f);
    unsigned r = (u + 0x7FFFu + ((u >> 16) & 1u)) >> 16;
    return (short)r;
}
__device__ __forceinline__ float b2f(short s) {
    unsigned u = ((unsigned)(unsigned short)s) << 16;
    return __builtin_bit_cast(float, u);
}
__device__ __forceinline__ void gll16(const void* g, void* l) {
    // global -> LDS direct, 16B/lane; LDS dest = wave-uniform base + lane*16
    __builtin_amdgcn_global_load_lds(
        (const __attribute__((address_space(1))) unsigned int*)g,
        (__attribute__((address_space(3))) unsigned int*)l, 16, 0, 0);
}

// ---------------------------------------------------------------------------
__global__ __launch_bounds__(256) void convert_f32_bf16(
    const float* __restrict__ in, short* __restrict__ out, int n)
{
    int i = (blockIdx.x * 256 + threadIdx.x) * 4;
    if (i < n) {
        float4 v = *(const float4*)(in + i);
        short4 o;
        o.x = f2b(v.x); o.y = f2b(v.y); o.z = f2b(v.z); o.w = f2b(v.w);
        *(short4*)(out + i) = o;
    }
}

// in [K][N] fp32 -> out [N][K] bf16 (i.e. B^T for the GEMM)
__global__ __launch_bounds__(256) void transpose_conv(
    const float* __restrict__ in, short* __restrict__ out, int K, int N)
{
    __shared__ float t[64][65];
    const int k0 = blockIdx.y * 64, n0 = blockIdx.x * 64;
    const int tid = threadIdx.x;
#pragma unroll
    for (int rep = 0; rep < 16; ++rep) {
        int flat = rep * 256 + tid;
        int r = flat >> 6, c = flat & 63;
        t[r][c] = in[(size_t)(k0 + r) * N + n0 + c];
    }
    __syncthreads();
#pragma unroll
    for (int rep = 0; rep < 16; ++rep) {
        int flat = rep * 256 + tid;
        int r = flat >> 6, c = flat & 63;
        out[(size_t)(n0 + r) * K + k0 + c] = f2b(t[c][r]);
    }
}

// ---------------------------------------------------------------------------
// bf16 GEMM, m97 structure (unchanged this round).
// ---------------------------------------------------------------------------
template <int MODE>
__global__ __launch_bounds__(256) void gemm_bf16(
    const short* __restrict__ A, const short* __restrict__ Bt,
    const float* __restrict__ bias,
    short* __restrict__ Qb, short* __restrict__ Kb, short* __restrict__ Vt,
    float* __restrict__ C, int M, int N, int K)
{
    __shared__ __align__(16) short As[128 * 32];
    __shared__ __align__(16) short Bs[128 * 32];

    const int tid = threadIdx.x;
    const int lane = tid & 63, w = tid >> 6;
    const int l15 = lane & 15, l4 = lane >> 4;
    const int wm = w >> 1, wn = w & 1;
    const int m0 = blockIdx.y * 128, n0 = blockIdx.x * 128;

    f32x4 acc[4][4];
#pragma unroll
    for (int i = 0; i < 4; ++i)
#pragma unroll
        for (int j = 0; j < 4; ++j) acc[i][j] = (f32x4)0.f;

    for (int k0 = 0; k0 < K; k0 += 32) {
        __syncthreads();
#pragma unroll
        for (int i = 0; i < 2; ++i) {
            const int slot = w * 64 + i * 256 + lane;      // 0..511
            const int row = slot >> 2, cb = slot & 3;      // 4x16B per 32-col row
            char* ldst = (char*)As + (w * 64 + i * 256) * 16;  // wave-uniform
            gll16(A + (size_t)(m0 + row) * K + k0 + cb * 8, ldst);
            char* ldst2 = (char*)Bs + (w * 64 + i * 256) * 16;
            gll16(Bt + (size_t)(n0 + row) * K + k0 + cb * 8, ldst2);
        }
        __syncthreads();

        bf16x8 af[4], bfr[4];
#pragma unroll
        for (int f = 0; f < 4; ++f) {
            af[f]  = *(const bf16x8*)((const char*)As + ((wm * 64 + f * 16 + l15) * 32 + l4 * 8) * 2);
            bfr[f] = *(const bf16x8*)((const char*)Bs + ((wn * 64 + f * 16 + l15) * 32 + l4 * 8) * 2);
        }
#pragma unroll
        for (int fm = 0; fm < 4; ++fm)
#pragma unroll
            for (int fn = 0; fn < 4; ++fn)
                acc[fm][fn] = __builtin_amdgcn_mfma_f32_16x16x32_bf16(
                    af[fm], bfr[fn], acc[fm][fn], 0, 0, 0);
    }

    // epilogue: C/D layout col = lane&15, row = (lane>>4)*4 + r
#pragma unroll
    for (int fn = 0; fn < 4; ++fn) {
        const int n = n0 + wn * 64 + fn * 16 + l15;
        const float bv = bias[n];
        if (MODE == 0) {
            const int sel = n >> 10, nq = n & 1023, hh = nq >> 6, dd = nq & 63;
#pragma unroll
            for (int fm = 0; fm < 4; ++fm)
#pragma unroll
                for (int r = 0; r < 4; ++r) {
                    const int mrow = m0 + wm * 64 + fm * 16 + l4 * 4 + r;
                    const short hv = f2b(acc[fm][fn][r] + bv);
                    const int bb = mrow >> 11, tt = mrow & 2047;
                    const size_t bh = (size_t)(bb * Hc + hh);
                    if (sel == 0)      Qb[(bh * Tc + tt) * Dc + dd] = hv;
                    else if (sel == 1) Kb[(bh * Tc + tt) * Dc + dd] = hv;
                    else               Vt[(bh * Dc + dd) * Tc + tt] = hv;
                }
        } else {
#pragma unroll
            for (int fm = 0; fm < 4; ++fm)
#pragma unroll
                for (int r = 0; r < 4; ++r) {
                    const int mrow = m0 + wm * 64 + fm * 16 + l4 * 4 + r;
                    C[(size_t)mrow * N + n] = acc[fm][fn][r] + bv;
                }
        }
    }
}

// ---------------------------------------------------------------------------
// Flash attention v2: swapped QK^T (S^T = K·Q) so each lane owns ONE q-row
// (q = lane&15) -> per-lane scalar softmax state, 4 shuffles/tile total.
// P never touches LDS: PV B-fragments built by an 8x64b shuffle exchange.
// PV also swapped (O^T = Vt·P^T) so the alpha-rescale is in-lane.
// K/V double-buffered via global_load_lds; 1 barrier per tile.
// ---------------------------------------------------------------------------
__global__ __launch_bounds__(256) void attn_mfma2(
    const short* __restrict__ Qg, const short* __restrict__ Kg,
    const short* __restrict__ Vtg, short* __restrict__ Ab)
{
    __shared__ __align__(16) short Ks[2][64 * 64];
    __shared__ __align__(16) short Vs[2][64 * 64];   // Vt tile: rows d, cols s

    const int tid = threadIdx.x;
    const int lane = tid & 63, w = tid >> 6;
    const int l15 = lane & 15, l4 = lane >> 4;
    const int tq = (int)gridDim.x - 1 - (int)blockIdx.x;  // long blocks first
    const int h = blockIdx.y, b = blockIdx.z;
    const size_t base = (size_t)(b * Hc + h) * Tc * Dc;   // same extent Q,K,Vt
    const int q0 = tq * 64 + w * 16;                      // wave's q-rows

    // Q fragments (B-operand of swapped QK): lane holds q-row l15,
    // d = kf*32 + l4*8 .. +8.  Pre-scaled by 1/sqrt(D)=0.125 (exact in bf16).
    bf16x8 qf[2];
    {
        const short* qp = Qg + base + (size_t)(q0 + l15) * Dc + l4 * 8;
        qf[0] = *(const bf16x8*)qp;
        qf[1] = *(const bf16x8*)(qp + 32);
#pragma unroll
        for (int e = 0; e < 8; ++e) {
            qf[0][e] = f2b(b2f(qf[0][e]) * 0.125f);
            qf[1][e] = f2b(b2f(qf[1][e]) * 0.125f);
        }
    }

    f32x4 ot[4];                 // O^T: d = fd*16 + l4*4 + r, q = l15
    float mr = -1e30f, ls = 0.f; // per-lane (q = l15) running stats
#pragma unroll
    for (int i = 0; i < 4; ++i) ot[i] = (f32x4)0.f;

    // shuffle-exchange constants (see derivation in round notes)
    const int srcA = l15 + (((2 * l4) & 3) << 4);
    const int srcB = l15 + (((2 * l4 + 1) & 3) << 4);
    const bool hiFn = ((l4 >> 1) & 1) != 0;

    // prologue: stage tile 0 into buffer 0
#pragma unroll
    for (int i = 0; i < 2; ++i) {
        const int slot = w * 64 + i * 256 + lane;
        const int row = slot >> 3, cb = slot & 7;
        const int cbs = cb ^ (row & 7);               // pre-swizzled source
        gll16(Kg + base + (size_t)row * Dc + cbs * 8,
              (char*)&Ks[0][0] + (w * 64 + i * 256) * 16);
        gll16(Vtg + base + (size_t)row * Tc + cbs * 8,
              (char*)&Vs[0][0] + (w * 64 + i * 256) * 16);
    }
    asm volatile("s_waitcnt vmcnt(0)" ::: "memory");
    __syncthreads();

    for (int st = 0; st <= tq; ++st) {
        const int cur = st & 1;
        if (st < tq) {  // prefetch next tile into the other buffer
            const int nx = cur ^ 1;
#pragma unroll
            for (int i = 0; i < 2; ++i) {
                const int slot = w * 64 + i * 256 + lane;
                const int row = slot >> 3, cb = slot & 7;
                const int cbs = cb ^ (row & 7);
                gll16(Kg + base + (size_t)((st + 1) * 64 + row) * Dc + cbs * 8,
                      (char*)&Ks[nx][0] + (w * 64 + i * 256) * 16);
                gll16(Vtg + base + (size_t)row * Tc + (st + 1) * 64 + cbs * 8,
                      (char*)&Vs[nx][0] + (w * 64 + i * 256) * 16);
            }
        }

        // S^T = K·Q : lane holds q=l15, key = fn*16 + l4*4 + r
        const char* Kc = (const char*)&Ks[cur][0];
        const char* Vc = (const char*)&Vs[cur][0];
        f32x4 s[4];
#pragma unroll
        for (int fn = 0; fn < 4; ++fn) s[fn] = (f32x4)0.f;
#pragma unroll
        for (int kf = 0; kf < 2; ++kf)
#pragma unroll
            for (int fn = 0; fn < 4; ++fn) {
                const int srow = fn * 16 + l15;   // key row in K tile
                bf16x8 kb = *(const bf16x8*)(Kc + srow * 128 +
                                             ((kf * 64 + l4 * 16) ^ ((srow & 7) << 4)));
                s[fn] = __builtin_amdgcn_mfma_f32_16x16x32_bf16(kb, qf[kf], s[fn], 0, 0, 0);
            }

        if (st == tq) {  // causal mask: key > q  (tile-local indices)
#pragma unroll
            for (int fn = 0; fn < 4; ++fn)
#pragma unroll
                for (int r = 0; r < 4; ++r)
                    if (fn * 16 + l4 * 4 + r > w * 16 + l15) s[fn][r] = -1e30f;
        }

        // online softmax, fully per-lane (q = l15); 64 keys split over 4 l4-groups
        float tm = -1e30f;
#pragma unroll
        for (int fn = 0; fn < 4; ++fn)
#pragma unroll
            for (int r = 0; r < 4; ++r) tm = fmaxf(tm, s[fn][r]);
        tm = fmaxf(tm, __shfl_xor(tm, 16));
        tm = fmaxf(tm, __shfl_xor(tm, 32));
        const float mn = fmaxf(mr, tm);
        const float alpha = __expf(mr - mn);
        mr = mn;
        float rs = 0.f;
#pragma unroll
        for (int fn = 0; fn < 4; ++fn)
#pragma unroll
            for (int r = 0; r < 4; ++r) {
                const float p = __expf(s[fn][r] - mn);
                s[fn][r] = p;
                rs += p;
            }
        rs += __shfl_xor(rs, 16);
        rs += __shfl_xor(rs, 32);
        ls = ls * alpha + rs;

        // pack P to bf16 quads: plo[fn] = [r0 r1 r2 r3] for q=l15
        unsigned long long plo[4];
#pragma unroll
        for (int fn = 0; fn < 4; ++fn) {
            unsigned lo = (unsigned)(unsigned short)f2b(s[fn][0]) |
                          ((unsigned)(unsigned short)f2b(s[fn][1]) << 16);
            unsigned hi = (unsigned)(unsigned short)f2b(s[fn][2]) |
                          ((unsigned)(unsigned short)f2b(s[fn][3]) << 16);
            plo[fn] = (unsigned long long)lo | ((unsigned long long)hi << 32);
        }

        // build PV B-fragments by shuffle exchange:
        // pb[kf] elem e <-> key k = kf*32 + l4*8 + e
        bf16x8 pb[2];
#pragma unroll
        for (int kf = 0; kf < 2; ++kf) {
            unsigned long long a0 = __shfl(plo[kf * 2],     srcA, 64);
            unsigned long long a1 = __shfl(plo[kf * 2 + 1], srcA, 64);
            unsigned long long b0 = __shfl(plo[kf * 2],     srcB, 64);
            unsigned long long b1 = __shfl(plo[kf * 2 + 1], srcB, 64);
            union { unsigned long long u[2]; bf16x8 v; } cvt;
            cvt.u[0] = hiFn ? a1 : a0;
            cvt.u[1] = hiFn ? b1 : b0;
            pb[kf] = cvt.v;
        }

        // rescale O^T (in-lane) then O^T += Vt · P^T
#pragma unroll
        for (int fd = 0; fd < 4; ++fd)
#pragma unroll
            for (int r = 0; r < 4; ++r) ot[fd][r] *= alpha;
#pragma unroll
        for (int kf = 0; kf < 2; ++kf)
#pragma unroll
            for (int fd = 0; fd < 4; ++fd) {
                const int vrow = fd * 16 + l15;   // d row in Vt tile
                bf16x8 va = *(const bf16x8*)(Vc + vrow * 128 +
                                             ((kf * 64 + l4 * 16) ^ ((vrow & 7) << 4)));
                ot[fd] = __builtin_amdgcn_mfma_f32_16x16x32_bf16(va, pb[kf], ot[fd], 0, 0, 0);
            }

        if (st < tq) {
            asm volatile("s_waitcnt vmcnt(0)" ::: "memory");
            __syncthreads();
        }
    }

    // normalize + store: row q = q0 + l15, cols d = fd*16 + l4*4 + 0..3
    const float inv = 1.f / ls;
    const size_t rowb = (size_t)(b * Tc + q0 + l15) * Ec + h * Dc;
#pragma unroll
    for (int fd = 0; fd < 4; ++fd) {
        short4 r4;
        r4.x = f2b(ot[fd][0] * inv);
        r4.y = f2b(ot[fd][1] * inv);
        r4.z = f2b(ot[fd][2] * inv);
        r4.w = f2b(ot[fd][3] * inv);
        *(short4*)(Ab + rowb + fd * 16 + l4 * 4) = r4;
    }
}

// ---------------------------------------------------------------------------
extern "C" void kernel_launch(void* const* d_in, const int* in_sizes, int n_in,
                              void* d_out, int out_size, void* d_ws, size_t ws_size,
                              hipStream_t stream)
{
    const float* x     = (const float*)d_in[0];
    const float* w_qkv = (const float*)d_in[1];
    const float* b_qkv = (const float*)d_in[2];
    const float* w_out = (const float*)d_in[3];
    const float* b_out = (const float*)d_in[4];
    float* out = (float*)d_out;

    const size_t NX = (size_t)8192 * 1024;
    short* xb  = (short*)d_ws;        // 16 MB
    short* Wtq = xb + NX;             // [3072][1024] bf16
    short* Wto = Wtq + (size_t)3072 * 1024;  // [1024][1024] bf16
    short* Qb  = Wto + (size_t)1024 * 1024;  // [B,H,T,D] bf16
    short* Kb  = Qb + NX;
    short* Vt  = Kb + NX;             // [B,H,D,T] bf16
    short* Ab  = Vt + NX;             // [B*T][E] bf16

    convert_f32_bf16<<<8192, 256, 0, stream>>>(x, xb, (int)NX);
    transpose_conv<<<dim3(48, 16), 256, 0, stream>>>(w_qkv, Wtq, 1024, 3072);
    transpose_conv<<<dim3(16, 16), 256, 0, stream>>>(w_out, Wto, 1024, 1024);

    gemm_bf16<0><<<dim3(24, 64), 256, 0, stream>>>(
        xb, Wtq, b_qkv, Qb, Kb, Vt, nullptr, 8192, 3072, 1024);

    attn_mfma2<<<dim3(32, 16, 4), 256, 0, stream>>>(Qb, Kb, Vt, Ab);

    gemm_bf16<1><<<dim3(8, 64), 256, 0, stream>>>(
        Ab, Wto, b_out, nullptr, nullptr, nullptr, out, 8192, 1024, 1024);
}